// Round 6
// baseline (438.750 us; speedup 1.0000x reference)
//
#include <hip/hip_runtime.h>
#include <hip/hip_bf16.h>
#include <stdint.h>

// PixproLoss: out = -(sum_masked cos_sim / count_mask), B=2048, C=256, P=49.
// R8 = R5 Gram numerics (G[p,q]=sum_c b[c,p]*m[c,q] via MFMA, bf16 operands,
// fp32 norms) with ALL global loads made linearly coalesced:
//   e = (tid + r*512)*4, float4 -> wave reads 1KB contiguous (16 lines vs ~64
//   scattered at the old 196B lane stride). Transpose happens in LDS via
//   per-element bf16 scatter stores; c = e/49 by magic mul (21401>>20, exact
//   for e<14364). fp32 norms via ds_add_f32 atomics on LDS (error ~1e-9).
// Theory: R3/R5 both stuck at 92us because vmem was line-transaction bound
// (lane-stride-196B fragments every load); occupancy was never the limiter
// (R6/R7: 80% occ + spills = slower).
// Lessons kept: loads consumed before next barrier; no cross-barrier register
// prefetch; no 64-reg occupancy gamble (512,4: LDS-capped 2 blocks/CU).

typedef __attribute__((ext_vector_type(8))) short short8;
typedef __attribute__((ext_vector_type(4))) float floatx4;

#define P 49
#define CP 12544           // C*P
#define NMASK 2401         // P*P
#define MT_STRIDE 264      // bf16 units; row = 528 B (16B-aligned; 132 dw = 4 mod 32 banks)
#define WS_STRIDE 72       // bf16 units; row = 144 B

__device__ __forceinline__ uint16_t f2bf(float x) {   // RNE f32->bf16
  union { float f; uint32_t u; } v; v.f = x;
  uint32_t r = v.u + 0x7fffu + ((v.u >> 16) & 1u);
  return (uint16_t)(r >> 16);
}
__device__ __forceinline__ float bf2f(uint16_t h) {
  union { uint32_t u; float f; } v; v.u = ((uint32_t)h) << 16; return v.f;
}

__global__ __launch_bounds__(512, 4) void pixpro_main(
    const float* __restrict__ base, const float* __restrict__ moment,
    const int* __restrict__ A, float* __restrict__ ws_num, float* __restrict__ ws_cnt)
{
  __shared__ __align__(16) uint16_t mT[P * MT_STRIDE];   // m^T[q][c] bf16: 25.9 KB
  __shared__ __align__(16) uint16_t bT[P * MT_STRIDE];   // b^T[p][c] bf16: 25.9 KB
  __shared__ __align__(16) uint16_t wS[P * WS_STRIDE];   // mask*inv_nb*inv_nm bf16: 6.9 KB
  __shared__ __align__(16) float nmA[P];                 // fp32 nm^2 (atomic)
  __shared__ __align__(16) float nbA[P];                 // fp32 nb^2 (atomic)
  __shared__ float numredS[8], cntredS[8];

  const int b    = blockIdx.x;
  const int tid  = threadIdx.x;
  const int lane = tid & 63;
  const int wv   = tid >> 6;          // 0..7
  const int mrow = lane & 15;
  const int kgrp = (lane >> 4) & 3;

  const float* gb = base   + (size_t)b * CP;
  const float* gm = moment + (size_t)b * CP;
  const int*   gA = A      + (size_t)b * NMASK;

  // ---- zero norm accumulators, then barrier Z (nothing in flight: cheap) ----
  if (tid < P) { nmA[tid] = 0.f; nbA[tid] = 0.f; }
  __syncthreads();

  // ---- Phase M: coalesced linear load of moment -> mT scatter + nm atomics ----
  #pragma unroll
  for (int r = 0; r < 7; ++r) {
    const int e0 = (tid + r * 512) * 4;
    if (e0 < CP) {                       // rounds 0..5 full; round 6: tid<64
      float4 v = *(const float4*)(gm + e0);
      int c = (int)(((unsigned)e0 * 21401u) >> 20);   // e0/49, exact for e0<14364
      int q = e0 - c * 49;
      float vals[4] = {v.x, v.y, v.z, v.w};
      #pragma unroll
      for (int j = 0; j < 4; ++j) {
        atomicAdd(&nmA[q], vals[j] * vals[j]);
        mT[q * MT_STRIDE + c] = f2bf(vals[j]);
        if (++q == 49) { q = 0; ++c; }
      }
    }
  }

  // ---- A-mask loads (issued now; consumed after barrier A as registers) ----
  const bool btask = tid < P * 8;     // 392 tasks: p = tid>>3, q-group = tid&7
  const int  bp    = tid >> 3;
  const int  bqg   = tid & 7;
  const int  bq0   = bqg * 8;
  int bmask[8];
  #pragma unroll
  for (int j = 0; j < 8; ++j) bmask[j] = 0;
  if (btask) {
    const int* Ar = gA + bp * P + bq0;
    if (bqg <= 5) {                   // q <= 47, fully valid
      int4 u0 = *(const int4*)(Ar);
      int4 u1 = *(const int4*)(Ar + 4);
      bmask[0] = u0.x; bmask[1] = u0.y; bmask[2] = u0.z; bmask[3] = u0.w;
      bmask[4] = u1.x; bmask[5] = u1.y; bmask[6] = u1.z; bmask[7] = u1.w;
    } else if (bqg == 6) {            // only q=48 valid
      bmask[0] = Ar[0];
    }
  }

  // ---- Phase B: coalesced linear load of base -> bT scatter + nb atomics ----
  #pragma unroll
  for (int r = 0; r < 7; ++r) {
    const int e0 = (tid + r * 512) * 4;
    if (e0 < CP) {
      float4 v = *(const float4*)(gb + e0);
      int c = (int)(((unsigned)e0 * 21401u) >> 20);
      int p = e0 - c * 49;
      float vals[4] = {v.x, v.y, v.z, v.w};
      #pragma unroll
      for (int j = 0; j < 4; ++j) {
        atomicAdd(&nbA[p], vals[j] * vals[j]);
        bT[p * MT_STRIDE + c] = f2bf(vals[j]);
        if (++p == 49) { p = 0; ++c; }
      }
    }
  }

  __syncthreads();   // barrier A: mT, bT, nmA, nbA visible

  // ---- wS build: wS[p][q] = mask ? inv_nb[p]*inv_nm[q] : 0 (bf16) ----
  int cntpart = 0;
  if (btask) {
    const float inb = 1.0f / fmaxf(sqrtf(nbA[bp]), 1e-6f);
    float wf[8];
    #pragma unroll
    for (int j = 0; j < 8; ++j) {
      const int q = bq0 + j;
      const float inm = (q < P) ? (1.0f / fmaxf(sqrtf(nmA[q]), 1e-6f)) : 0.f;
      wf[j] = bmask[j] ? inb * inm : 0.f;
      cntpart += bmask[j];
    }
    short8 w8;
    #pragma unroll
    for (int j = 0; j < 8; ++j) w8[j] = (short)f2bf(wf[j]);
    *(short8*)&wS[bp * WS_STRIDE + bq0] = w8;      // 16B-aligned
  }

  // ---- MFMA: G tiles. Wave wv: pt = wv&3, qt in {2*(wv>>2), +1}. ----
  // A-frag = bT[pbase+mrow][k], B-frag = mT[qbase+mrow][k]; 16B ds_read_b128.
  const int pt   = wv & 3;
  const int qt1i = 2 * (wv >> 2) + 1;                 // qt0 = qt1i-1 in {0,2}
  const int pbaseV = (pt < 3) ? pt * 16 : 33;         // tiles {0,16,32,33}, dedup below
  const int qbase0 = (qt1i - 1) * 16;                 // 0 or 32
  const int qbase1 = (qt1i < 3) ? qt1i * 16 : 33;

  const int arow  = (pbaseV + mrow) * MT_STRIDE;
  const int brow0 = (qbase0 + mrow) * MT_STRIDE;
  const int brow1 = (qbase1 + mrow) * MT_STRIDE;

  floatx4 acc0 = (floatx4){0.f, 0.f, 0.f, 0.f};
  floatx4 acc1 = (floatx4){0.f, 0.f, 0.f, 0.f};
  #pragma unroll
  for (int ks = 0; ks < 8; ++ks) {
    const int off = ks * 32 + kgrp * 8;
    short8 af  = *(const short8*)&bT[arow  + off];
    short8 bf0 = *(const short8*)&mT[brow0 + off];
    short8 bf1 = *(const short8*)&mT[brow1 + off];
    acc0 = __builtin_amdgcn_mfma_f32_16x16x32_bf16(af, bf0, acc0, 0, 0, 0);
    acc1 = __builtin_amdgcn_mfma_f32_16x16x32_bf16(af, bf1, acc1, 0, 0, 0);
  }

  __syncthreads();   // barrier B: wS visible

  // ---- Epilogue: num_part = sum wS[p][q] * G[p][q] over owned D elems ----
  // D: q = qbase + (lane&15), p = pbase + kgrp*4 + r. Dedup tile 3 (rows 33..48).
  const bool vq1 = (qt1i < 3) || (mrow == 15);
  const int  q0r = qbase0 + mrow;
  const int  q1r = qbase1 + mrow;
  float numpart = 0.f;
  #pragma unroll
  for (int r = 0; r < 4; ++r) {
    const int rr = kgrp * 4 + r;
    const int p  = pbaseV + rr;
    const bool vp = (pt < 3) || (rr == 15);
    if (vp) {
      float w0 = bf2f(wS[p * WS_STRIDE + q0r]);
      float w1 = vq1 ? bf2f(wS[p * WS_STRIDE + q1r]) : 0.f;
      numpart = fmaf(w0, acc0[r], numpart);
      numpart = fmaf(w1, acc1[r], numpart);
    }
  }

  // full-wave reduce
  float cntf = (float)cntpart;
  #pragma unroll
  for (int off = 32; off > 0; off >>= 1) {
    numpart += __shfl_xor(numpart, off);
    cntf    += __shfl_xor(cntf, off);
  }
  if (lane == 0) { numredS[wv] = numpart; cntredS[wv] = cntf; }
  __syncthreads();   // barrier C

  if (tid < 64) {
    float n = (tid < 8) ? numredS[tid] : 0.f;
    float c = (tid < 8) ? cntredS[tid] : 0.f;
    #pragma unroll
    for (int off = 4; off > 0; off >>= 1) {
      n += __shfl_xor(n, off);
      c += __shfl_xor(c, off);
    }
    if (tid == 0) { ws_num[b] = n; ws_cnt[b] = c; }
  }
}

__global__ __launch_bounds__(256) void pixpro_reduce(
    const float* __restrict__ ws_num, const float* __restrict__ ws_cnt,
    float* __restrict__ out)
{
  __shared__ float rn[4], rc[4];
  float n = 0.f, c = 0.f;
  for (int i = threadIdx.x; i < 2048; i += 256) { n += ws_num[i]; c += ws_cnt[i]; }
  #pragma unroll
  for (int off = 32; off > 0; off >>= 1) {
    n += __shfl_down(n, off, 64);
    c += __shfl_down(c, off, 64);
  }
  const int wv = threadIdx.x >> 6, lane = threadIdx.x & 63;
  if (lane == 0) { rn[wv] = n; rc[wv] = c; }
  __syncthreads();
  if (threadIdx.x == 0) {
    float N = rn[0] + rn[1] + rn[2] + rn[3];
    float D = rc[0] + rc[1] + rc[2] + rc[3];
    out[0] = -(N / D);
  }
}

extern "C" void kernel_launch(void* const* d_in, const int* in_sizes, int n_in,
                              void* d_out, int out_size, void* d_ws, size_t ws_size,
                              hipStream_t stream) {
  const float* base   = (const float*)d_in[0];
  const float* moment = (const float*)d_in[1];
  const int*   A      = (const int*)d_in[2];
  float* ws_num = (float*)d_ws;          // 2048 floats
  float* ws_cnt = ws_num + 2048;         // 2048 floats
  pixpro_main<<<2048, 512, 0, stream>>>(base, moment, A, ws_num, ws_cnt);
  pixpro_reduce<<<1, 256, 0, stream>>>(ws_num, ws_cnt, (float*)d_out);
}

// Round 7
// 285.055 us; speedup vs baseline: 1.5392x; 1.5392x over previous
//
#include <hip/hip_runtime.h>
#include <hip/hip_bf16.h>
#include <stdint.h>

// PixproLoss: out = -(sum_masked cos_sim / count_mask), B=2048, C=256, P=49.
// R9 = phase-decomposed pipeline (ablation + candidate):
//   K1 pixpro_norms: inv_nb[b][p], inv_nm[b][q] via the strided scalar-read
//      pattern in isolation (no barriers, no LDS, full occupancy). Its dur_us
//      is the decisive measurement: is fragmented vmem the 92us limiter?
//   K2 pixpro_gram: R3's verified MFMA body minus all norm computation:
//      loads -> maskS build -> bar -> MFMA -> b-loads+accum -> bar -> write.
//      inv_nb is a precomputed constant, so num contributions sum flat
//      (no per-p S[] assembly, no SQred, 2 barriers instead of 4).
//   K3 pixpro_reduce: unchanged.
// ws layout (floats): [0:2048) num, [2048:4096) cnt,
//   [4096 : 4096+2048*64) inv_nb (64-padded/b), then 2048*64 inv_nm. ~1.04 MB.
// Lessons kept: no LDS atomics; no cross-barrier reg prefetch; loads consumed
// before next barrier; AGPR counts in the (512,6)=85 budget (R3-proven fit).

typedef __attribute__((ext_vector_type(8))) short short8;
typedef __attribute__((ext_vector_type(4))) float floatx4;

#define P 49
#define CP 12544           // C*P
#define NMASK 2401         // P*P
#define MS_STRIDE 72       // maskS LDS row stride (bf16): 64 data + 8 pad

__device__ __forceinline__ short8 cvt8(float4 a, float4 b) {
  union { __hip_bfloat162 h2; short s2[2]; } t;
  short8 r;
  t.h2 = __float22bfloat162_rn(make_float2(a.x, a.y)); r[0] = t.s2[0]; r[1] = t.s2[1];
  t.h2 = __float22bfloat162_rn(make_float2(a.z, a.w)); r[2] = t.s2[0]; r[3] = t.s2[1];
  t.h2 = __float22bfloat162_rn(make_float2(b.x, b.y)); r[4] = t.s2[0]; r[5] = t.s2[1];
  t.h2 = __float22bfloat162_rn(make_float2(b.z, b.w)); r[6] = t.s2[0]; r[7] = t.s2[1];
  return r;
}

// ---- K1: norms only. thread (q = tid>>3, cg = tid&7) sums 32 channels of
// both matrices via strided scalar reads; 8-lane shuffle combine; write inv. ----
__global__ __launch_bounds__(512, 8) void pixpro_norms(
    const float* __restrict__ base, const float* __restrict__ moment,
    float* __restrict__ invb_g, float* __restrict__ invm_g)
{
  const int b   = blockIdx.x;
  const int tid = threadIdx.x;
  const int q   = tid >> 3;          // 0..63 (q >= 49 idle)
  const int cg  = tid & 7;           // channel group: c = cg*32 .. +31
  float am = 0.f, ab = 0.f;
  if (q < P) {
    const float* pm = moment + (size_t)b * CP + (cg * 32) * P + q;
    const float* pb = base   + (size_t)b * CP + (cg * 32) * P + q;
    #pragma unroll
    for (int i = 0; i < 32; ++i) {
      const float vm = pm[i * P];
      const float vb = pb[i * P];
      am = fmaf(vm, vm, am);
      ab = fmaf(vb, vb, ab);
    }
  }
  // sum over cg (lane bits 0..2)
  am += __shfl_xor(am, 1); am += __shfl_xor(am, 2); am += __shfl_xor(am, 4);
  ab += __shfl_xor(ab, 1); ab += __shfl_xor(ab, 2); ab += __shfl_xor(ab, 4);
  if (cg == 0 && q < P) {
    invm_g[b * 64 + q] = 1.0f / fmaxf(sqrtf(am), 1e-6f);
    invb_g[b * 64 + q] = 1.0f / fmaxf(sqrtf(ab), 1e-6f);
  }
}

// ---- K2: R3 MFMA body, norms precomputed ----
__global__ __launch_bounds__(512, 6) void pixpro_gram(
    const float* __restrict__ base, const float* __restrict__ moment,
    const int* __restrict__ A, const float* __restrict__ invb_g,
    const float* __restrict__ invm_g,
    float* __restrict__ ws_num, float* __restrict__ ws_cnt)
{
  __shared__ __align__(16) uint16_t maskS[P * MS_STRIDE];      // mask*inv_nm bf16: 7.1 KB
  __shared__ __align__(16) float invBs[52];
  __shared__ float numred[8], cntred[8];

  const int b    = blockIdx.x;
  const int tid  = threadIdx.x;
  const int lane = tid & 63;
  const int wv   = tid >> 6;          // 0..7
  const int mrow = lane & 15;
  const int kgrp = (lane >> 4) & 3;

  const float* gb = base   + (size_t)b * CP;
  const float* gm = moment + (size_t)b * CP;
  const int*   gA = A      + (size_t)b * NMASK;

  // ---- m-frag loads (R3 P1 pattern; wave wv owns c-tiles 2wv, 2wv+1) ----
  short8 afrag[2][2];                 // [cti][kt]
  #pragma unroll
  for (int cti = 0; cti < 2; ++cti) {
    const int c = (2 * wv + cti) * 16 + mrow;
    const float* row = gm + c * P;
    float4 a0 = *(const float4*)(row + kgrp * 8);
    float4 a1 = *(const float4*)(row + kgrp * 8 + 4);
    float4 b0, b1;
    if (kgrp < 2) {
      b0 = *(const float4*)(row + 32 + kgrp * 8);
      b1 = *(const float4*)(row + 32 + kgrp * 8 + 4);
    } else if (kgrp == 2) {
      b0 = make_float4(row[48], 0.f, 0.f, 0.f);   // q=48 only; always in-bounds
      b1 = make_float4(0.f, 0.f, 0.f, 0.f);
    } else {
      b0 = make_float4(0.f, 0.f, 0.f, 0.f);
      b1 = make_float4(0.f, 0.f, 0.f, 0.f);
    }
    afrag[cti][0] = cvt8(a0, a1);
    afrag[cti][1] = cvt8(b0, b1);
  }

  // ---- A-mask loads ----
  const bool btask = tid < P * 8;     // p = tid>>3, q-group = tid&7
  const int  bp    = tid >> 3;
  const int  bqg   = tid & 7;
  const int  bq0   = bqg * 8;
  int bmask[8];
  #pragma unroll
  for (int j = 0; j < 8; ++j) bmask[j] = 0;
  if (btask) {
    const int* Ar = gA + bp * P + bq0;
    if (bqg <= 5) {
      int4 u0 = *(const int4*)(Ar);
      int4 u1 = *(const int4*)(Ar + 4);
      bmask[0] = u0.x; bmask[1] = u0.y; bmask[2] = u0.z; bmask[3] = u0.w;
      bmask[4] = u1.x; bmask[5] = u1.y; bmask[6] = u1.z; bmask[7] = u1.w;
    } else if (bqg == 6) {
      bmask[0] = Ar[0];
    }
  }

  // ---- inv_nb stage to LDS (consumed after bar1) ----
  if (tid < P) invBs[tid] = invb_g[b * 64 + tid];

  // ---- maskS build: maskS[p][q] = mask ? inv_nm[q] : 0 (bf16) ----
  int cntpart = 0;
  if (btask) {
    float4 i0 = *(const float4*)(invm_g + b * 64 + bq0);       // 16B-aligned (64b+8j)
    float4 i1 = *(const float4*)(invm_g + b * 64 + bq0 + 4);
    float4 f0, f1;
    f0.x = bmask[0] ? i0.x : 0.f; f0.y = bmask[1] ? i0.y : 0.f;
    f0.z = bmask[2] ? i0.z : 0.f; f0.w = bmask[3] ? i0.w : 0.f;
    f1.x = bmask[4] ? i1.x : 0.f; f1.y = bmask[5] ? i1.y : 0.f;
    f1.z = bmask[6] ? i1.z : 0.f; f1.w = bmask[7] ? i1.w : 0.f;
    #pragma unroll
    for (int j = 0; j < 8; ++j) cntpart += bmask[j];
    *(short8*)&maskS[bp * MS_STRIDE + bq0] = cvt8(f0, f1);
  }
  __syncthreads();   // bar1: maskS + invBs visible

  // ---- MFMA: m2 tiles; B-frag: lane -> B[k = kgrp*8+j][n = mrow] ----
  const int pbase[4] = {0, 16, 32, 33};   // tile 3 = rows 33..48 (dedup via invp)
  floatx4 acc[2][4];
  #pragma unroll
  for (int i = 0; i < 2; ++i)
    #pragma unroll
    for (int j = 0; j < 4; ++j) acc[i][j] = (floatx4){0.f, 0.f, 0.f, 0.f};

  #pragma unroll
  for (int kt = 0; kt < 2; ++kt) {
    short8 bfr[4];
    #pragma unroll
    for (int pt = 0; pt < 4; ++pt)
      bfr[pt] = *(const short8*)&maskS[(pbase[pt] + mrow) * MS_STRIDE + kt * 32 + kgrp * 8];
    #pragma unroll
    for (int cti = 0; cti < 2; ++cti)
      #pragma unroll
      for (int pt = 0; pt < 4; ++pt)
        acc[cti][pt] = __builtin_amdgcn_mfma_f32_16x16x32_bf16(afrag[cti][kt], bfr[pt], acc[cti][pt], 0, 0, 0);
  }

  // ---- Epilogue: numpart = sum inv_nb[p] * b[c,p] * m2[c,p] (flat fp32 sum) ----
  // D layout: col = lane&15 -> p-within-tile; row = kgrp*4+r -> c-within-tile.
  float numpart = 0.f;
  {
    float invp[4];
    #pragma unroll
    for (int pt = 0; pt < 4; ++pt) {
      const int pd = pbase[pt] + mrow;
      const bool pv = (pt < 3) || (mrow == 15);   // dedup rows 33..47 of tile 3
      invp[pt] = pv ? invBs[pd] : 0.f;
    }
    #pragma unroll
    for (int cti = 0; cti < 2; ++cti)
      #pragma unroll
      for (int pt = 0; pt < 4; ++pt) {
        const int pd = pbase[pt] + mrow;
        #pragma unroll
        for (int r = 0; r < 4; ++r) {
          const int c = (2 * wv + cti) * 16 + kgrp * 4 + r;
          numpart = fmaf(invp[pt] * gb[c * P + pd], acc[cti][pt][r], numpart);
        }
      }
  }

  // full-wave reduce (sum over kgrp, mrow, all lanes)
  float cntf = (float)cntpart;
  #pragma unroll
  for (int off = 32; off > 0; off >>= 1) {
    numpart += __shfl_xor(numpart, off);
    cntf    += __shfl_xor(cntf, off);
  }
  if (lane == 0) { numred[wv] = numpart; cntred[wv] = cntf; }
  __syncthreads();   // bar2

  if (tid < 64) {
    float n = (tid < 8) ? numred[tid] : 0.f;
    float c = (tid < 8) ? cntred[tid] : 0.f;
    #pragma unroll
    for (int off = 4; off > 0; off >>= 1) {
      n += __shfl_xor(n, off);
      c += __shfl_xor(c, off);
    }
    if (tid == 0) { ws_num[b] = n; ws_cnt[b] = c; }
  }
}

__global__ __launch_bounds__(256) void pixpro_reduce(
    const float* __restrict__ ws_num, const float* __restrict__ ws_cnt,
    float* __restrict__ out)
{
  __shared__ float rn[4], rc[4];
  float n = 0.f, c = 0.f;
  for (int i = threadIdx.x; i < 2048; i += 256) { n += ws_num[i]; c += ws_cnt[i]; }
  #pragma unroll
  for (int off = 32; off > 0; off >>= 1) {
    n += __shfl_down(n, off, 64);
    c += __shfl_down(c, off, 64);
  }
  const int wv = threadIdx.x >> 6, lane = threadIdx.x & 63;
  if (lane == 0) { rn[wv] = n; rc[wv] = c; }
  __syncthreads();
  if (threadIdx.x == 0) {
    float N = rn[0] + rn[1] + rn[2] + rn[3];
    float D = rc[0] + rc[1] + rc[2] + rc[3];
    out[0] = -(N / D);
  }
}

extern "C" void kernel_launch(void* const* d_in, const int* in_sizes, int n_in,
                              void* d_out, int out_size, void* d_ws, size_t ws_size,
                              hipStream_t stream) {
  const float* base   = (const float*)d_in[0];
  const float* moment = (const float*)d_in[1];
  const int*   A      = (const int*)d_in[2];
  float* ws_num = (float*)d_ws;              // 2048
  float* ws_cnt = ws_num + 2048;             // 2048
  float* invb_g = ws_cnt + 2048;             // 2048*64 (64-padded per b)
  float* invm_g = invb_g + 2048 * 64;        // 2048*64
  pixpro_norms<<<2048, 512, 0, stream>>>(base, moment, invb_g, invm_g);
  pixpro_gram<<<2048, 512, 0, stream>>>(base, moment, A, invb_g, invm_g, ws_num, ws_cnt);
  pixpro_reduce<<<1, 256, 0, stream>>>(ws_num, ws_cnt, (float*)d_out);
}

// Round 8
// 238.011 us; speedup vs baseline: 1.8434x; 1.1977x over previous
//
#include <hip/hip_runtime.h>
#include <hip/hip_bf16.h>
#include <stdint.h>

// PixproLoss: out = -(sum_masked cos_sim / count_mask), B=2048, C=256, P=49.
// R10 = single fused kernel, ONE coalesced cold pass (the R9 ablation showed the
// fragmented 196B-stride read pattern alone costs 100us cold vs 33us roofline;
// everything else is cheap). Structure:
//   linear float4 loads (1KB/wave contiguous) -> bf16 scatter to transposed LDS
//   (mT[q][c], bT[p][c]) -> barrier -> norms from LDS (b128 reads + 8-lane
//   shuffle, fp32 squares; NO atomics - R8's mistake) -> barrier -> wS build +
//   R5's verified Gram MFMA (G[p,q]=sum_c b[c,p]m[c,q]) -> barrier -> epilogue.
// Norms from bf16 values: est. +1e-8 output error (passes at 2.4e-7 today).
// Lessons: no LDS atomics; loads consumed before next barrier; no cross-barrier
// reg prefetch (except A-mask regs, R8-proven at 52 VGPR); AGPR counts in budget.

typedef __attribute__((ext_vector_type(8))) short short8;
typedef __attribute__((ext_vector_type(4))) float floatx4;

#define P 49
#define CP 12544           // C*P
#define NMASK 2401         // P*P
#define MT_STRIDE 264      // bf16 units; row = 528 B (16B-aligned)
#define WS_STRIDE 72       // bf16 units; row = 144 B

__device__ __forceinline__ uint16_t f2bf(float x) {   // RNE f32->bf16
  union { float f; uint32_t u; } v; v.f = x;
  uint32_t r = v.u + 0x7fffu + ((v.u >> 16) & 1u);
  return (uint16_t)(r >> 16);
}
__device__ __forceinline__ float bf2f(uint16_t h) {
  union { uint32_t u; float f; } v; v.u = ((uint32_t)h) << 16; return v.f;
}

__global__ __launch_bounds__(512, 4) void pixpro_main(
    const float* __restrict__ base, const float* __restrict__ moment,
    const int* __restrict__ A, float* __restrict__ ws_num, float* __restrict__ ws_cnt)
{
  __shared__ __align__(16) uint16_t mT[P * MT_STRIDE];   // m^T[q][c] bf16: 25.9 KB
  __shared__ __align__(16) uint16_t bT[P * MT_STRIDE];   // b^T[p][c] bf16: 25.9 KB
  __shared__ __align__(16) uint16_t wS[P * WS_STRIDE];   // mask*inv_nb*inv_nm bf16: 6.9 KB
  __shared__ __align__(16) float invB[64];               // 1/max(||b_p||,eps), 49..63 = 0
  __shared__ __align__(16) float invM[64];               // 1/max(||m_q||,eps), 49..63 = 0
  __shared__ float numredS[8], cntredS[8];

  const int b    = blockIdx.x;
  const int tid  = threadIdx.x;
  const int lane = tid & 63;
  const int wv   = tid >> 6;          // 0..7
  const int mrow = lane & 15;
  const int kgrp = (lane >> 4) & 3;

  const float* gb = base   + (size_t)b * CP;
  const float* gm = moment + (size_t)b * CP;
  const int*   gA = A      + (size_t)b * NMASK;

  // ---- Phase M: coalesced linear load of moment -> mT bf16 scatter ----
  #pragma unroll
  for (int r = 0; r < 7; ++r) {
    const int e0 = (tid + r * 512) * 4;
    if (e0 < CP) {                       // rounds 0..5 full; round 6: tid<64
      float4 v = *(const float4*)(gm + e0);
      int c = (int)(((unsigned)e0 * 21401u) >> 20);   // e0/49, exact for e0<14364
      int q = e0 - c * 49;
      float vals[4] = {v.x, v.y, v.z, v.w};
      #pragma unroll
      for (int j = 0; j < 4; ++j) {
        mT[q * MT_STRIDE + c] = f2bf(vals[j]);
        if (++q == 49) { q = 0; ++c; }
      }
    }
  }

  // ---- A-mask loads (issued now; consumed after barrier A2 as registers) ----
  const bool btask = tid < P * 8;     // 392 tasks: p = tid>>3, q-group = tid&7
  const int  bp    = tid >> 3;
  const int  bqg   = tid & 7;
  const int  bq0   = bqg * 8;
  int bmask[8];
  #pragma unroll
  for (int j = 0; j < 8; ++j) bmask[j] = 0;
  if (btask) {
    const int* Ar = gA + bp * P + bq0;
    if (bqg <= 5) {                   // q <= 47, fully valid
      int4 u0 = *(const int4*)(Ar);
      int4 u1 = *(const int4*)(Ar + 4);
      bmask[0] = u0.x; bmask[1] = u0.y; bmask[2] = u0.z; bmask[3] = u0.w;
      bmask[4] = u1.x; bmask[5] = u1.y; bmask[6] = u1.z; bmask[7] = u1.w;
    } else if (bqg == 6) {            // only q=48 valid
      bmask[0] = Ar[0];
    }
  }

  // ---- Phase B: coalesced linear load of base -> bT bf16 scatter ----
  #pragma unroll
  for (int r = 0; r < 7; ++r) {
    const int e0 = (tid + r * 512) * 4;
    if (e0 < CP) {
      float4 v = *(const float4*)(gb + e0);
      int c = (int)(((unsigned)e0 * 21401u) >> 20);
      int p = e0 - c * 49;
      float vals[4] = {v.x, v.y, v.z, v.w};
      #pragma unroll
      for (int j = 0; j < 4; ++j) {
        bT[p * MT_STRIDE + c] = f2bf(vals[j]);
        if (++p == 49) { p = 0; ++c; }
      }
    }
  }

  __syncthreads();   // barrier A: mT, bT visible

  // ---- Phase N: norms from LDS bf16 (no atomics). Thread (bp, bqg) sums
  // squares of 32 columns of row bp in BOTH matrices; 8-lane shuffle combine. ----
  if (btask) {
    float nb2 = 0.f, nm2 = 0.f;
    #pragma unroll
    for (int u = 0; u < 4; ++u) {
      short8 xb = *(const short8*)&bT[bp * MT_STRIDE + bqg * 32 + u * 8];
      short8 xm = *(const short8*)&mT[bp * MT_STRIDE + bqg * 32 + u * 8];
      #pragma unroll
      for (int j = 0; j < 8; ++j) {
        float fb = bf2f((uint16_t)xb[j]);
        float fm = bf2f((uint16_t)xm[j]);
        nb2 = fmaf(fb, fb, nb2);
        nm2 = fmaf(fm, fm, nm2);
      }
    }
    nb2 += __shfl_xor(nb2, 1); nb2 += __shfl_xor(nb2, 2); nb2 += __shfl_xor(nb2, 4);
    nm2 += __shfl_xor(nm2, 1); nm2 += __shfl_xor(nm2, 2); nm2 += __shfl_xor(nm2, 4);
    if (bqg == 0) {
      invB[bp] = 1.0f / fmaxf(sqrtf(nb2), 1e-6f);
      invM[bp] = 1.0f / fmaxf(sqrtf(nm2), 1e-6f);
    }
  } else if (tid >= 496) {            // pad 49..63 with zeros (16 spare threads)
    const int i = 49 + (tid - 496);
    if (i < 64) { invB[i] = 0.f; invM[i] = 0.f; }
  }
  __syncthreads();   // barrier A2: invB, invM visible

  // ---- wS build: wS[p][q] = mask ? inv_nb[p]*inv_nm[q] : 0 (bf16) ----
  int cntpart = 0;
  if (btask) {
    const float inb = invB[bp];
    float4 i0 = *(const float4*)&invM[bq0];
    float4 i1 = *(const float4*)&invM[bq0 + 4];
    float4 f0, f1;
    f0.x = bmask[0] ? inb * i0.x : 0.f; f0.y = bmask[1] ? inb * i0.y : 0.f;
    f0.z = bmask[2] ? inb * i0.z : 0.f; f0.w = bmask[3] ? inb * i0.w : 0.f;
    f1.x = bmask[4] ? inb * i1.x : 0.f; f1.y = bmask[5] ? inb * i1.y : 0.f;
    f1.z = bmask[6] ? inb * i1.z : 0.f; f1.w = bmask[7] ? inb * i1.w : 0.f;
    #pragma unroll
    for (int j = 0; j < 8; ++j) cntpart += bmask[j];
    union { __hip_bfloat162 h2; short s2[2]; } t;
    short8 w8;
    t.h2 = __float22bfloat162_rn(make_float2(f0.x, f0.y)); w8[0] = t.s2[0]; w8[1] = t.s2[1];
    t.h2 = __float22bfloat162_rn(make_float2(f0.z, f0.w)); w8[2] = t.s2[0]; w8[3] = t.s2[1];
    t.h2 = __float22bfloat162_rn(make_float2(f1.x, f1.y)); w8[4] = t.s2[0]; w8[5] = t.s2[1];
    t.h2 = __float22bfloat162_rn(make_float2(f1.z, f1.w)); w8[6] = t.s2[0]; w8[7] = t.s2[1];
    *(short8*)&wS[bp * WS_STRIDE + bq0] = w8;      // 16B-aligned
  }

  // ---- MFMA: G tiles (R5-verified). Wave wv: pt = wv&3, qt in {2*(wv>>2), +1}. ----
  const int pt   = wv & 3;
  const int qt1i = 2 * (wv >> 2) + 1;                 // qt0 = qt1i-1 in {0,2}
  const int pbaseV = (pt < 3) ? pt * 16 : 33;         // tiles {0,16,32,33}, dedup below
  const int qbase0 = (qt1i - 1) * 16;                 // 0 or 32
  const int qbase1 = (qt1i < 3) ? qt1i * 16 : 33;

  const int arow  = (pbaseV + mrow) * MT_STRIDE;
  const int brow0 = (qbase0 + mrow) * MT_STRIDE;
  const int brow1 = (qbase1 + mrow) * MT_STRIDE;

  floatx4 acc0 = (floatx4){0.f, 0.f, 0.f, 0.f};
  floatx4 acc1 = (floatx4){0.f, 0.f, 0.f, 0.f};
  #pragma unroll
  for (int ks = 0; ks < 8; ++ks) {
    const int off = ks * 32 + kgrp * 8;
    short8 af  = *(const short8*)&bT[arow  + off];
    short8 bf0 = *(const short8*)&mT[brow0 + off];
    short8 bf1 = *(const short8*)&mT[brow1 + off];
    acc0 = __builtin_amdgcn_mfma_f32_16x16x32_bf16(af, bf0, acc0, 0, 0, 0);
    acc1 = __builtin_amdgcn_mfma_f32_16x16x32_bf16(af, bf1, acc1, 0, 0, 0);
  }

  __syncthreads();   // barrier B: wS visible

  // ---- Epilogue: num_part = sum wS[p][q] * G[p][q] over owned D elems ----
  // D: q = qbase + (lane&15), p = pbase + kgrp*4 + r. Dedup tile 3 (rows 33..48).
  const bool vq1 = (qt1i < 3) || (mrow == 15);
  const int  q0r = qbase0 + mrow;
  const int  q1r = qbase1 + mrow;
  float numpart = 0.f;
  #pragma unroll
  for (int r = 0; r < 4; ++r) {
    const int rr = kgrp * 4 + r;
    const int p  = pbaseV + rr;
    const bool vp = (pt < 3) || (rr == 15);
    if (vp) {
      float w0 = bf2f(wS[p * WS_STRIDE + q0r]);
      float w1 = vq1 ? bf2f(wS[p * WS_STRIDE + q1r]) : 0.f;
      numpart = fmaf(w0, acc0[r], numpart);
      numpart = fmaf(w1, acc1[r], numpart);
    }
  }

  // full-wave reduce
  float cntf = (float)cntpart;
  #pragma unroll
  for (int off = 32; off > 0; off >>= 1) {
    numpart += __shfl_xor(numpart, off);
    cntf    += __shfl_xor(cntf, off);
  }
  if (lane == 0) { numredS[wv] = numpart; cntredS[wv] = cntf; }
  __syncthreads();   // barrier C

  if (tid < 64) {
    float n = (tid < 8) ? numredS[tid] : 0.f;
    float c = (tid < 8) ? cntredS[tid] : 0.f;
    #pragma unroll
    for (int off = 4; off > 0; off >>= 1) {
      n += __shfl_xor(n, off);
      c += __shfl_xor(c, off);
    }
    if (tid == 0) { ws_num[b] = n; ws_cnt[b] = c; }
  }
}

__global__ __launch_bounds__(256) void pixpro_reduce(
    const float* __restrict__ ws_num, const float* __restrict__ ws_cnt,
    float* __restrict__ out)
{
  __shared__ float rn[4], rc[4];
  float n = 0.f, c = 0.f;
  for (int i = threadIdx.x; i < 2048; i += 256) { n += ws_num[i]; c += ws_cnt[i]; }
  #pragma unroll
  for (int off = 32; off > 0; off >>= 1) {
    n += __shfl_down(n, off, 64);
    c += __shfl_down(c, off, 64);
  }
  const int wv = threadIdx.x >> 6, lane = threadIdx.x & 63;
  if (lane == 0) { rn[wv] = n; rc[wv] = c; }
  __syncthreads();
  if (threadIdx.x == 0) {
    float N = rn[0] + rn[1] + rn[2] + rn[3];
    float D = rc[0] + rc[1] + rc[2] + rc[3];
    out[0] = -(N / D);
  }
}

extern "C" void kernel_launch(void* const* d_in, const int* in_sizes, int n_in,
                              void* d_out, int out_size, void* d_ws, size_t ws_size,
                              hipStream_t stream) {
  const float* base   = (const float*)d_in[0];
  const float* moment = (const float*)d_in[1];
  const int*   A      = (const int*)d_in[2];
  float* ws_num = (float*)d_ws;          // 2048 floats
  float* ws_cnt = ws_num + 2048;         // 2048 floats
  pixpro_main<<<2048, 512, 0, stream>>>(base, moment, A, ws_num, ws_cnt);
  pixpro_reduce<<<1, 256, 0, stream>>>(ws_num, ws_cnt, (float*)d_out);
}